// Round 2
// baseline (637.580 us; speedup 1.0000x reference)
//
#include <hip/hip_runtime.h>
#include <math.h>

// ---------------------------------------------------------------------------
// TransformerBlock with relative position bias, MI355X (gfx950).
// B=8 S=512 H=16 DM=1024 DFF=4096 DK=64.  All heavy GEMMs in bf16 MFMA
// (16x16x32), epilogues in fp32.
// Round 1: GEMM staging via global_load_lds (width 16) — m97 structure.
// ---------------------------------------------------------------------------

typedef unsigned short ushort_t;
typedef __attribute__((ext_vector_type(8))) short short8;
typedef __attribute__((ext_vector_type(4))) float f32x4;
typedef __attribute__((ext_vector_type(8))) __bf16 bf16x8;

__device__ __forceinline__ float b2f(ushort_t u) {
  unsigned v = (unsigned)u << 16;
  return __builtin_bit_cast(float, v);
}
__device__ __forceinline__ ushort_t f2b(float f) {
  unsigned x = __builtin_bit_cast(unsigned, f);
  x = x + 0x7fffu + ((x >> 16) & 1u);   // round-to-nearest-even
  return (ushort_t)(x >> 16);
}

// async global->LDS, 16 bytes per lane. lds dest must be wave-uniform base;
// HW adds lane*16.  Global src is per-lane.
__device__ __forceinline__ void gload16(const ushort_t* g, ushort_t* l) {
  __builtin_amdgcn_global_load_lds(
      (const __attribute__((address_space(1))) unsigned*)g,
      (__attribute__((address_space(3))) unsigned*)l, 16, 0, 0);
}

// ---------------------------------------------------------------- convert ---
__global__ void k_f32_to_bf16(const float* __restrict__ in,
                              ushort_t* __restrict__ out, long long n) {
  long long i = ((long long)blockIdx.x * blockDim.x + threadIdx.x) * 4;
  if (i >= n) return;
  float4 v = *reinterpret_cast<const float4*>(in + i);
  ushort4 o;
  o.x = f2b(v.x); o.y = f2b(v.y); o.z = f2b(v.z); o.w = f2b(v.w);
  *reinterpret_cast<ushort4*>(out + i) = o;
}

// -------------------------------------------------------------- layernorm ---
__global__ void k_layernorm_bf16(const float* __restrict__ x,
                                 const float* __restrict__ g,
                                 const float* __restrict__ b,
                                 ushort_t* __restrict__ out) {
  const int lane = threadIdx.x & 63;
  const int row = (blockIdx.x << 2) + (threadIdx.x >> 6);
  const float* xr = x + (long long)row * 1024;
  float4 v[4];
  float s = 0.f, ss = 0.f;
#pragma unroll
  for (int i = 0; i < 4; ++i) {
    v[i] = *reinterpret_cast<const float4*>(xr + lane * 16 + i * 4);
    s += v[i].x + v[i].y + v[i].z + v[i].w;
    ss += v[i].x * v[i].x + v[i].y * v[i].y + v[i].z * v[i].z + v[i].w * v[i].w;
  }
#pragma unroll
  for (int o = 32; o > 0; o >>= 1) {
    s += __shfl_xor(s, o);
    ss += __shfl_xor(ss, o);
  }
  float mean = s * (1.f / 1024.f);
  float var = (ss - 1024.f * mean * mean) * (1.f / 1023.f);
  var = fmaxf(var, 0.f);
  float inv = 1.f / (sqrtf(var) + 1e-6f);
  ushort_t* orow = out + (long long)row * 1024;
#pragma unroll
  for (int i = 0; i < 4; ++i) {
    int c = lane * 16 + i * 4;
    ushort4 o;
    o.x = f2b(g[c + 0] * (v[i].x - mean) * inv + b[c + 0]);
    o.y = f2b(g[c + 1] * (v[i].y - mean) * inv + b[c + 1]);
    o.z = f2b(g[c + 2] * (v[i].z - mean) * inv + b[c + 2]);
    o.w = f2b(g[c + 3] * (v[i].w - mean) * inv + b[c + 3]);
    *reinterpret_cast<ushort4*>(orow + c) = o;
  }
}

// ---------------------------------------------------------------- softmax ---
__global__ void k_softmax(ushort_t* __restrict__ sc, const int* __restrict__ mask,
                          float scale) {
  const int lane = threadIdx.x & 63;
  const long long row = ((long long)blockIdx.x << 2) + (threadIdx.x >> 6);
  const int b = (int)(row >> 13);
  ushort_t* srow = sc + row * 512;
  const int* mrow = mask + b * 512;
  short8 sv = *reinterpret_cast<const short8*>(srow + lane * 8);
  float vals[8];
  float mx = -1e30f;
#pragma unroll
  for (int j = 0; j < 8; ++j) {
    float f = b2f((ushort_t)sv[j]) * scale;
    if (mrow[lane * 8 + j] == 0) f = -1e9f;
    vals[j] = f;
    mx = fmaxf(mx, f);
  }
#pragma unroll
  for (int o = 32; o > 0; o >>= 1) mx = fmaxf(mx, __shfl_xor(mx, o));
  float s = 0.f;
#pragma unroll
  for (int j = 0; j < 8; ++j) {
    vals[j] = __expf(vals[j] - mx);
    s += vals[j];
  }
#pragma unroll
  for (int o = 32; o > 0; o >>= 1) s += __shfl_xor(s, o);
  float inv = 1.f / s;
  short8 ov;
#pragma unroll
  for (int j = 0; j < 8; ++j) ov[j] = (short)f2b(vals[j] * inv);
  *reinterpret_cast<short8*>(srow + lane * 8) = ov;
}

// ---------------------------------------------------- transpose v (bf16) ----
__global__ void k_transpose_v(const ushort_t* __restrict__ v,
                              ushort_t* __restrict__ vT) {
  __shared__ ushort_t tls[64][72];
  const int bh = blockIdx.y;
  const int s0 = blockIdx.x << 6;
  const int t = threadIdx.x;
  const long long base = (long long)bh * 32768;
#pragma unroll
  for (int it = 0; it < 2; ++it) {
    int r = (t >> 3) + it * 32;
    int c = (t & 7) << 3;
    short8 val = *reinterpret_cast<const short8*>(v + base + (long long)(s0 + r) * 64 + c);
    *reinterpret_cast<short8*>(&tls[r][c]) = val;
  }
  __syncthreads();
#pragma unroll
  for (int it = 0; it < 2; ++it) {
    int d = (t >> 3) + it * 32;
    int cs = (t & 7) << 3;
    short8 o;
#pragma unroll
    for (int j = 0; j < 8; ++j) o[j] = (short)tls[cs + j][d];
    *reinterpret_cast<short8*>(vT + base + (long long)d * 512 + s0 + cs) = o;
  }
}

// ------------------------------------------- transpose r_v (f32 -> bf16) ----
__global__ void k_transpose_rv(const float* __restrict__ rv,
                               ushort_t* __restrict__ rvT) {
  __shared__ float tls[64][65];
  const int q = blockIdx.y;
  const int k0 = blockIdx.x << 6;
  const int t = threadIdx.x;
  const long long ibase = (long long)q * 32768;
#pragma unroll
  for (int it = 0; it < 4; ++it) {
    int r = (t >> 4) + it * 16;
    int c = (t & 15) << 2;
    float4 val = *reinterpret_cast<const float4*>(rv + ibase + (long long)(k0 + r) * 64 + c);
    tls[r][c] = val.x; tls[r][c + 1] = val.y; tls[r][c + 2] = val.z; tls[r][c + 3] = val.w;
  }
  __syncthreads();
#pragma unroll
  for (int it = 0; it < 2; ++it) {
    int d = (t >> 3) + it * 32;
    int cs = (t & 7) << 3;
    short8 o;
#pragma unroll
    for (int j = 0; j < 8; ++j) o[j] = (short)f2b(tls[cs + j][d]);
    *reinterpret_cast<short8*>(rvT + ibase + (long long)d * 512 + k0 + cs) = o;
  }
}

// ------------------------------------------------- reshape attn to tokens ---
__global__ void k_reshape_attn(const ushort_t* __restrict__ a,
                               ushort_t* __restrict__ o) {
  long long i = (long long)blockIdx.x * 256 + threadIdx.x;
  int col8 = (int)(i & 127);
  long long tok = i >> 7;
  int col = col8 << 3;
  int h = col >> 6, d = col & 63;
  int bb = (int)(tok >> 9), s = (int)(tok & 511);
  short8 v = *reinterpret_cast<const short8*>(
      a + ((long long)(bb * 16 + h) * 512 + s) * 64 + d);
  *reinterpret_cast<short8*>(o + (tok << 10) + col) = v;
}

// ------------------------------------------------------------------ GEMM ----
// C[m,n] = scale * sum_k A[m,k]*B[n,k], batched via blockIdx.z.
// 128x128 tile, BK=32, 4 waves (2x2 of 64x64).  Staging: global_load_lds x16.
// MODE: 0 store bf16; 1 accumulate bf16; 2 QKV scatter (+bias);
//       3 f32 out = resid + acc + bias; 4 bf16 out = gelu(acc + bias).
struct GArgs {
  const ushort_t* A; const ushort_t* B;
  long long a_bs, b_bs, c_bs;
  long long a_rs, b_rs, c_rs;
  int M, N, K;
  float scale;
  ushort_t* Cb;
  float* Cf;
  const float* bias;
  const float* resid;
  ushort_t* qb; ushort_t* kb; ushort_t* vb;
};

template <int MODE>
__global__ __launch_bounds__(256) void k_gemm_bt(GArgs g) {
  __shared__ ushort_t As[128 * 32];
  __shared__ ushort_t Bs[128 * 32];
  const int t = threadIdx.x;
  const int lane = t & 63;
  const int w = t >> 6, wr = w >> 1, wc = w & 1;
  const long long z = blockIdx.z;
  const int m0 = blockIdx.y * 128, n0 = blockIdx.x * 128;
  const ushort_t* Ab = g.A + z * g.a_bs;
  const ushort_t* Bb = g.B + z * g.b_bs;
  const int sr = t >> 2;            // staged row within 64-row half
  const int sc = (t & 3) << 3;      // staged col (elements)
  const long long ar0 = min(m0 + sr, g.M - 1);
  const long long ar1 = min(m0 + sr + 64, g.M - 1);
  const long long br0 = min(n0 + sr, g.N - 1);
  const long long br1 = min(n0 + sr + 64, g.N - 1);
  const ushort_t* Ap0 = Ab + ar0 * g.a_rs + sc;
  const ushort_t* Ap1 = Ab + ar1 * g.a_rs + sc;
  const ushort_t* Bp0 = Bb + br0 * g.b_rs + sc;
  const ushort_t* Bp1 = Bb + br1 * g.b_rs + sc;
  // wave-uniform LDS staging bases (HW adds lane*16 bytes)
  ushort_t* AsW0 = As + w * 512;
  ushort_t* AsW1 = As + 2048 + w * 512;
  ushort_t* BsW0 = Bs + w * 512;
  ushort_t* BsW1 = Bs + 2048 + w * 512;

  f32x4 acc[4][4];
#pragma unroll
  for (int i = 0; i < 4; ++i)
#pragma unroll
    for (int j = 0; j < 4; ++j) acc[i][j] = f32x4{0.f, 0.f, 0.f, 0.f};

  const int fr = lane & 15;
  const int fkb = (lane >> 4) << 3;
  const int a_off0 = (wr * 64 + fr) * 32 + fkb;
  const int b_off0 = (wc * 64 + fr) * 32 + fkb;

  const int nkt = g.K >> 5;
  for (int kt = 0; kt < nkt; ++kt) {
    const int k0 = kt << 5;
    __syncthreads();                 // prev iter's ds_reads complete
    gload16(Ap0 + k0, AsW0);
    gload16(Ap1 + k0, AsW1);
    gload16(Bp0 + k0, BsW0);
    gload16(Bp1 + k0, BsW1);
    __syncthreads();                 // vmcnt(0) drain: tile resident
    bf16x8 af[4], bfv[4];
#pragma unroll
    for (int i = 0; i < 4; ++i)
      af[i] = *reinterpret_cast<const bf16x8*>(&As[a_off0 + i * 16 * 32]);
#pragma unroll
    for (int j = 0; j < 4; ++j)
      bfv[j] = *reinterpret_cast<const bf16x8*>(&Bs[b_off0 + j * 16 * 32]);
#pragma unroll
    for (int i = 0; i < 4; ++i)
#pragma unroll
      for (int j = 0; j < 4; ++j)
        acc[i][j] = __builtin_amdgcn_mfma_f32_16x16x32_bf16(af[i], bfv[j],
                                                            acc[i][j], 0, 0, 0);
  }

  const int er0 = wr * 64 + ((lane >> 4) << 2);
  const int ec0 = wc * 64 + (lane & 15);
#pragma unroll
  for (int i = 0; i < 4; ++i) {
#pragma unroll
    for (int j = 0; j < 4; ++j) {
#pragma unroll
      for (int r = 0; r < 4; ++r) {
        int row = m0 + er0 + i * 16 + r;
        int col = n0 + ec0 + j * 16;
        if (row >= g.M || col >= g.N) continue;
        float val = acc[i][j][r] * g.scale;
        if constexpr (MODE == 0) {
          g.Cb[z * g.c_bs + (long long)row * g.c_rs + col] = f2b(val);
        } else if constexpr (MODE == 1) {
          long long idx = z * g.c_bs + (long long)row * g.c_rs + col;
          g.Cb[idx] = f2b(b2f(g.Cb[idx]) + val);
        } else if constexpr (MODE == 2) {
          val += g.bias[col];
          int which = col >> 10;
          int h = (col >> 6) & 15;
          int d = col & 63;
          int bb = row >> 9, s = row & 511;
          ushort_t* dst = (which == 0) ? g.qb : (which == 1) ? g.kb : g.vb;
          dst[((long long)(bb * 16 + h) * 512 + s) * 64 + d] = f2b(val);
        } else if constexpr (MODE == 3) {
          long long idx = z * g.c_bs + (long long)row * g.c_rs + col;
          g.Cf[idx] = g.resid[idx] + val + g.bias[col];
        } else if constexpr (MODE == 4) {
          float xv = val + g.bias[col];
          float tv = tanhf(0.7978845608028654f * (xv + 0.044715f * xv * xv * xv));
          g.Cb[z * g.c_bs + (long long)row * g.c_rs + col] =
              f2b(0.5f * xv * (1.f + tv));
        }
      }
    }
  }
}

// ------------------------------------------------------------------ host ----
extern "C" void kernel_launch(void* const* d_in, const int* in_sizes, int n_in,
                              void* d_out, int out_size, void* d_ws,
                              size_t ws_size, hipStream_t stream) {
  const float* x    = (const float*)d_in[0];
  const int*   mask = (const int*)d_in[1];
  const float* Wq   = (const float*)d_in[2];
  const float* bq   = (const float*)d_in[3];
  const float* Wk   = (const float*)d_in[4];
  const float* bk   = (const float*)d_in[5];
  const float* Wv   = (const float*)d_in[6];
  const float* bv   = (const float*)d_in[7];
  const float* Wo   = (const float*)d_in[8];
  const float* bo   = (const float*)d_in[9];
  const float* r_k  = (const float*)d_in[10];
  const float* r_v  = (const float*)d_in[11];
  const float* ln1g = (const float*)d_in[12];
  const float* ln1b = (const float*)d_in[13];
  const float* ln2g = (const float*)d_in[14];
  const float* ln2b = (const float*)d_in[15];
  const float* w1   = (const float*)d_in[16];
  const float* b1   = (const float*)d_in[17];
  const float* w2   = (const float*)d_in[18];
  const float* b2   = (const float*)d_in[19];
  float* out = (float*)d_out;

  char* ws = (char*)d_ws;
  size_t off = 0;
  auto alloc = [&](size_t bytes) -> void* {
    void* p = ws + off;
    off += (bytes + 255) & ~(size_t)255;
    return p;
  };
  ushort_t* wqkv = (ushort_t*)alloc(3072ll * 1024 * 2);
  ushort_t* wo_b = (ushort_t*)alloc(1024ll * 1024 * 2);
  ushort_t* w1_b = (ushort_t*)alloc(4096ll * 1024 * 2);
  ushort_t* w2_b = (ushort_t*)alloc(1024ll * 4096 * 2);
  ushort_t* rk_b = (ushort_t*)alloc(512ll * 512 * 64 * 2);
  ushort_t* rvT  = (ushort_t*)alloc(512ll * 64 * 512 * 2);
  ushort_t* xn   = (ushort_t*)alloc(4096ll * 1024 * 2);  // later: attn_tok
  ushort_t* qb   = (ushort_t*)alloc(128ll * 512 * 64 * 2);  // later: h_bf
  ushort_t* kb   = (ushort_t*)alloc(128ll * 512 * 64 * 2);
  ushort_t* vb   = (ushort_t*)alloc(128ll * 512 * 64 * 2);
  ushort_t* vT   = (ushort_t*)alloc(128ll * 64 * 512 * 2);
  ushort_t* scp  = (ushort_t*)alloc(128ll * 512 * 512 * 2);  // later: mid
  ushort_t* attn = (ushort_t*)alloc(128ll * 512 * 64 * 2);
  float*    x1   = (float*)alloc(4096ll * 1024 * 4);
  float*    bqkv = (float*)alloc(3072 * 4);
  ushort_t* attn_tok = xn;
  ushort_t* h_b = qb;
  ushort_t* mid = scp;

  hipMemcpyAsync(bqkv, bq, 1024 * 4, hipMemcpyDeviceToDevice, stream);
  hipMemcpyAsync(bqkv + 1024, bk, 1024 * 4, hipMemcpyDeviceToDevice, stream);
  hipMemcpyAsync(bqkv + 2048, bv, 1024 * 4, hipMemcpyDeviceToDevice, stream);

  auto cvt = [&](const float* src, ushort_t* dst, long long n) {
    k_f32_to_bf16<<<dim3((unsigned)((n / 4 + 255) / 256)), 256, 0, stream>>>(src, dst, n);
  };
  cvt(Wq, wqkv, 1024ll * 1024);
  cvt(Wk, wqkv + 1024ll * 1024, 1024ll * 1024);
  cvt(Wv, wqkv + 2048ll * 1024, 1024ll * 1024);
  cvt(Wo, wo_b, 1024ll * 1024);
  cvt(w1, w1_b, 4096ll * 1024);
  cvt(w2, w2_b, 1024ll * 4096);
  cvt(r_k, rk_b, 512ll * 512 * 64);
  k_transpose_rv<<<dim3(8, 512), 256, 0, stream>>>(r_v, rvT);

  k_layernorm_bf16<<<1024, 256, 0, stream>>>(x, ln1g, ln1b, xn);

  {  // QKV projection, scatter to [B,H,S,DK]
    GArgs a{};
    a.A = xn; a.B = wqkv; a.a_rs = 1024; a.b_rs = 1024;
    a.M = 4096; a.N = 3072; a.K = 1024; a.scale = 1.f;
    a.bias = bqkv; a.qb = qb; a.kb = kb; a.vb = vb;
    k_gemm_bt<2><<<dim3(24, 32, 1), 256, 0, stream>>>(a);
  }

  k_transpose_v<<<dim3(8, 128), 256, 0, stream>>>(vb, vT);

  {  // scores = q.k^T (unscaled), per bh
    GArgs s{};
    s.A = qb; s.B = kb; s.a_bs = 32768; s.b_bs = 32768; s.c_bs = 262144;
    s.a_rs = 64; s.b_rs = 64; s.c_rs = 512;
    s.M = 512; s.N = 512; s.K = 64; s.scale = 1.f; s.Cb = scp;
    k_gemm_bt<0><<<dim3(4, 4, 128), 256, 0, stream>>>(s);
  }
  {  // scores += q . r_k[q]^T, per q-position (M=b*h)
    GArgs r{};
    r.A = qb; r.B = rk_b; r.a_bs = 64; r.b_bs = 32768; r.c_bs = 512;
    r.a_rs = 32768; r.b_rs = 64; r.c_rs = 262144;
    r.M = 128; r.N = 512; r.K = 64; r.scale = 1.f; r.Cb = scp;
    k_gemm_bt<1><<<dim3(4, 1, 512), 256, 0, stream>>>(r);
  }

  k_softmax<<<16384, 256, 0, stream>>>(scp, mask, 0.125f);

  {  // attn = p @ v, per bh
    GArgs pv{};
    pv.A = scp; pv.B = vT; pv.a_bs = 262144; pv.b_bs = 32768; pv.c_bs = 32768;
    pv.a_rs = 512; pv.b_rs = 512; pv.c_rs = 64;
    pv.M = 512; pv.N = 64; pv.K = 512; pv.scale = 1.f; pv.Cb = attn;
    k_gemm_bt<0><<<dim3(1, 4, 128), 256, 0, stream>>>(pv);
  }
  {  // attn += p . r_v[q], per q-position
    GArgs pr{};
    pr.A = scp; pr.B = rvT; pr.a_bs = 512; pr.b_bs = 32768; pr.c_bs = 64;
    pr.a_rs = 262144; pr.b_rs = 512; pr.c_rs = 32768;
    pr.M = 128; pr.N = 64; pr.K = 512; pr.scale = 1.f; pr.Cb = attn;
    k_gemm_bt<1><<<dim3(1, 1, 512), 256, 0, stream>>>(pr);
  }

  k_reshape_attn<<<2048, 256, 0, stream>>>(attn, attn_tok);

  {  // x1 = x + attn_tok @ Wo^T + bo   (fp32)
    GArgs o{};
    o.A = attn_tok; o.B = wo_b; o.a_rs = 1024; o.b_rs = 1024; o.c_rs = 1024;
    o.M = 4096; o.N = 1024; o.K = 1024; o.scale = 1.f;
    o.Cf = x1; o.bias = bo; o.resid = x;
    k_gemm_bt<3><<<dim3(8, 32, 1), 256, 0, stream>>>(o);
  }

  k_layernorm_bf16<<<1024, 256, 0, stream>>>(x1, ln2g, ln2b, h_b);

  {  // mid = gelu(h @ w1^T + b1)
    GArgs f1{};
    f1.A = h_b; f1.B = w1_b; f1.a_rs = 1024; f1.b_rs = 1024; f1.c_rs = 4096;
    f1.M = 4096; f1.N = 4096; f1.K = 1024; f1.scale = 1.f;
    f1.Cb = mid; f1.bias = b1;
    k_gemm_bt<4><<<dim3(32, 32, 1), 256, 0, stream>>>(f1);
  }
  {  // out = x1 + mid @ w2^T + b2   (fp32)
    GArgs f2{};
    f2.A = mid; f2.B = w2_b; f2.a_rs = 4096; f2.b_rs = 4096; f2.c_rs = 1024;
    f2.M = 4096; f2.N = 1024; f2.K = 4096; f2.scale = 1.f;
    f2.Cf = out; f2.bias = b2; f2.resid = x1;
    k_gemm_bt<3><<<dim3(8, 32, 1), 256, 0, stream>>>(f2);
  }
}

// Round 3
// 600.469 us; speedup vs baseline: 1.0618x; 1.0618x over previous
//
#include <hip/hip_runtime.h>
#include <math.h>

// ---------------------------------------------------------------------------
// TransformerBlock with relative position bias, MI355X (gfx950).
// B=8 S=512 H=16 DM=1024 DFF=4096 DK=64.  bf16 MFMA (16x16x32), fp32 epilogues.
// Round 2: double-buffered LDS prefetch (T3-minimum 2-phase) + XCD swizzle.
// ---------------------------------------------------------------------------

typedef unsigned short ushort_t;
typedef __attribute__((ext_vector_type(8))) short short8;
typedef __attribute__((ext_vector_type(4))) float f32x4;
typedef __attribute__((ext_vector_type(8))) __bf16 bf16x8;

__device__ __forceinline__ float b2f(ushort_t u) {
  unsigned v = (unsigned)u << 16;
  return __builtin_bit_cast(float, v);
}
__device__ __forceinline__ ushort_t f2b(float f) {
  unsigned x = __builtin_bit_cast(unsigned, f);
  x = x + 0x7fffu + ((x >> 16) & 1u);   // round-to-nearest-even
  return (ushort_t)(x >> 16);
}

// async global->LDS, 16 bytes per lane. lds dest wave-uniform; HW adds lane*16.
__device__ __forceinline__ void gload16(const ushort_t* g, ushort_t* l) {
  __builtin_amdgcn_global_load_lds(
      (const __attribute__((address_space(1))) unsigned*)g,
      (__attribute__((address_space(3))) unsigned*)l, 16, 0, 0);
}

// ---------------------------------------------------------------- convert ---
__global__ void k_f32_to_bf16(const float* __restrict__ in,
                              ushort_t* __restrict__ out, long long n) {
  long long i = ((long long)blockIdx.x * blockDim.x + threadIdx.x) * 4;
  if (i >= n) return;
  float4 v = *reinterpret_cast<const float4*>(in + i);
  ushort4 o;
  o.x = f2b(v.x); o.y = f2b(v.y); o.z = f2b(v.z); o.w = f2b(v.w);
  *reinterpret_cast<ushort4*>(out + i) = o;
}

// -------------------------------------------------------------- layernorm ---
__global__ void k_layernorm_bf16(const float* __restrict__ x,
                                 const float* __restrict__ g,
                                 const float* __restrict__ b,
                                 ushort_t* __restrict__ out) {
  const int lane = threadIdx.x & 63;
  const int row = (blockIdx.x << 2) + (threadIdx.x >> 6);
  const float* xr = x + (long long)row * 1024;
  float4 v[4];
  float s = 0.f, ss = 0.f;
#pragma unroll
  for (int i = 0; i < 4; ++i) {
    v[i] = *reinterpret_cast<const float4*>(xr + lane * 16 + i * 4);
    s += v[i].x + v[i].y + v[i].z + v[i].w;
    ss += v[i].x * v[i].x + v[i].y * v[i].y + v[i].z * v[i].z + v[i].w * v[i].w;
  }
#pragma unroll
  for (int o = 32; o > 0; o >>= 1) {
    s += __shfl_xor(s, o);
    ss += __shfl_xor(ss, o);
  }
  float mean = s * (1.f / 1024.f);
  float var = (ss - 1024.f * mean * mean) * (1.f / 1023.f);
  var = fmaxf(var, 0.f);
  float inv = 1.f / (sqrtf(var) + 1e-6f);
  ushort_t* orow = out + (long long)row * 1024;
#pragma unroll
  for (int i = 0; i < 4; ++i) {
    int c = lane * 16 + i * 4;
    ushort4 o;
    o.x = f2b(g[c + 0] * (v[i].x - mean) * inv + b[c + 0]);
    o.y = f2b(g[c + 1] * (v[i].y - mean) * inv + b[c + 1]);
    o.z = f2b(g[c + 2] * (v[i].z - mean) * inv + b[c + 2]);
    o.w = f2b(g[c + 3] * (v[i].w - mean) * inv + b[c + 3]);
    *reinterpret_cast<ushort4*>(orow + c) = o;
  }
}

// ---------------------------------------------------------------- softmax ---
__global__ void k_softmax(ushort_t* __restrict__ sc, const int* __restrict__ mask,
                          float scale) {
  const int lane = threadIdx.x & 63;
  const long long row = ((long long)blockIdx.x << 2) + (threadIdx.x >> 6);
  const int b = (int)(row >> 13);
  ushort_t* srow = sc + row * 512;
  const int* mrow = mask + b * 512;
  short8 sv = *reinterpret_cast<const short8*>(srow + lane * 8);
  float vals[8];
  float mx = -1e30f;
#pragma unroll
  for (int j = 0; j < 8; ++j) {
    float f = b2f((ushort_t)sv[j]) * scale;
    if (mrow[lane * 8 + j] == 0) f = -1e9f;
    vals[j] = f;
    mx = fmaxf(mx, f);
  }
#pragma unroll
  for (int o = 32; o > 0; o >>= 1) mx = fmaxf(mx, __shfl_xor(mx, o));
  float s = 0.f;
#pragma unroll
  for (int j = 0; j < 8; ++j) {
    vals[j] = __expf(vals[j] - mx);
    s += vals[j];
  }
#pragma unroll
  for (int o = 32; o > 0; o >>= 1) s += __shfl_xor(s, o);
  float inv = 1.f / s;
  short8 ov;
#pragma unroll
  for (int j = 0; j < 8; ++j) ov[j] = (short)f2b(vals[j] * inv);
  *reinterpret_cast<short8*>(srow + lane * 8) = ov;
}

// ---------------------------------------------------- transpose v (bf16) ----
__global__ void k_transpose_v(const ushort_t* __restrict__ v,
                              ushort_t* __restrict__ vT) {
  __shared__ ushort_t tls[64][72];
  const int bh = blockIdx.y;
  const int s0 = blockIdx.x << 6;
  const int t = threadIdx.x;
  const long long base = (long long)bh * 32768;
#pragma unroll
  for (int it = 0; it < 2; ++it) {
    int r = (t >> 3) + it * 32;
    int c = (t & 7) << 3;
    short8 val = *reinterpret_cast<const short8*>(v + base + (long long)(s0 + r) * 64 + c);
    *reinterpret_cast<short8*>(&tls[r][c]) = val;
  }
  __syncthreads();
#pragma unroll
  for (int it = 0; it < 2; ++it) {
    int d = (t >> 3) + it * 32;
    int cs = (t & 7) << 3;
    short8 o;
#pragma unroll
    for (int j = 0; j < 8; ++j) o[j] = (short)tls[cs + j][d];
    *reinterpret_cast<short8*>(vT + base + (long long)d * 512 + s0 + cs) = o;
  }
}

// ------------------------------------------- transpose r_v (f32 -> bf16) ----
__global__ void k_transpose_rv(const float* __restrict__ rv,
                               ushort_t* __restrict__ rvT) {
  __shared__ float tls[64][65];
  const int q = blockIdx.y;
  const int k0 = blockIdx.x << 6;
  const int t = threadIdx.x;
  const long long ibase = (long long)q * 32768;
#pragma unroll
  for (int it = 0; it < 4; ++it) {
    int r = (t >> 4) + it * 16;
    int c = (t & 15) << 2;
    float4 val = *reinterpret_cast<const float4*>(rv + ibase + (long long)(k0 + r) * 64 + c);
    tls[r][c] = val.x; tls[r][c + 1] = val.y; tls[r][c + 2] = val.z; tls[r][c + 3] = val.w;
  }
  __syncthreads();
#pragma unroll
  for (int it = 0; it < 2; ++it) {
    int d = (t >> 3) + it * 32;
    int cs = (t & 7) << 3;
    short8 o;
#pragma unroll
    for (int j = 0; j < 8; ++j) o[j] = (short)f2b(tls[cs + j][d]);
    *reinterpret_cast<short8*>(rvT + ibase + (long long)d * 512 + k0 + cs) = o;
  }
}

// ------------------------------------------------- reshape attn to tokens ---
__global__ void k_reshape_attn(const ushort_t* __restrict__ a,
                               ushort_t* __restrict__ o) {
  long long i = (long long)blockIdx.x * 256 + threadIdx.x;
  int col8 = (int)(i & 127);
  long long tok = i >> 7;
  int col = col8 << 3;
  int h = col >> 6, d = col & 63;
  int bb = (int)(tok >> 9), s = (int)(tok & 511);
  short8 v = *reinterpret_cast<const short8*>(
      a + ((long long)(bb * 16 + h) * 512 + s) * 64 + d);
  *reinterpret_cast<short8*>(o + (tok << 10) + col) = v;
}

// ------------------------------------------------------------------ GEMM ----
// C[m,n] = scale * sum_k A[m,k]*B[n,k], batched via blockIdx.z.
// 128x128 tile, BK=32, 4 waves.  Double-buffered LDS, prefetch-next schedule:
//   prologue STAGE(buf0,0); loop { barrier(vmcnt0); STAGE(buf^1,t+1);
//   ds_read buf; MFMA }   (T3-minimum 2-phase recipe)
// MODE: 0 store bf16; 1 accumulate bf16; 2 QKV scatter (+bias);
//       3 f32 out = resid + acc + bias; 4 bf16 out = gelu(acc + bias).
struct GArgs {
  const ushort_t* A; const ushort_t* B;
  long long a_bs, b_bs, c_bs;
  long long a_rs, b_rs, c_rs;
  int M, N, K;
  float scale;
  ushort_t* Cb;
  float* Cf;
  const float* bias;
  const float* resid;
  ushort_t* qb; ushort_t* kb; ushort_t* vb;
  int swz;
};

template <int MODE>
__global__ __launch_bounds__(256) void k_gemm_bt(GArgs g) {
  __shared__ ushort_t As[2][128 * 32];
  __shared__ ushort_t Bs[2][128 * 32];
  const int t = threadIdx.x;
  const int lane = t & 63;
  const int w = t >> 6, wr = w >> 1, wc = w & 1;
  const long long z = blockIdx.z;

  int bx = blockIdx.x, by = blockIdx.y;
  if (g.swz) {  // bijective XCD swizzle (grids are multiples of 8)
    int nx = gridDim.x;
    int id = by * nx + bx;
    int cpx = (nx * gridDim.y) >> 3;
    id = (id & 7) * cpx + (id >> 3);
    bx = id % nx;
    by = id / nx;
  }
  const int m0 = by * 128, n0 = bx * 128;

  const ushort_t* Ab = g.A + z * g.a_bs;
  const ushort_t* Bb = g.B + z * g.b_bs;
  const int sr = t >> 2;            // staged row within 64-row half
  const int sc = (t & 3) << 3;      // staged col (elements)
  const long long ar0 = min(m0 + sr, g.M - 1);
  const long long ar1 = min(m0 + sr + 64, g.M - 1);
  const long long br0 = min(n0 + sr, g.N - 1);
  const long long br1 = min(n0 + sr + 64, g.N - 1);
  const ushort_t* Ap0 = Ab + ar0 * g.a_rs + sc;
  const ushort_t* Ap1 = Ab + ar1 * g.a_rs + sc;
  const ushort_t* Bp0 = Bb + br0 * g.b_rs + sc;
  const ushort_t* Bp1 = Bb + br1 * g.b_rs + sc;
  const int wofs = w * 512;

  f32x4 acc[4][4];
#pragma unroll
  for (int i = 0; i < 4; ++i)
#pragma unroll
    for (int j = 0; j < 4; ++j) acc[i][j] = f32x4{0.f, 0.f, 0.f, 0.f};

  const int fr = lane & 15;
  const int fkb = (lane >> 4) << 3;
  const int a_off0 = (wr * 64 + fr) * 32 + fkb;
  const int b_off0 = (wc * 64 + fr) * 32 + fkb;

  const int nkt = g.K >> 5;
  // prologue: stage tile 0 into buf 0
  gload16(Ap0, &As[0][wofs]);
  gload16(Ap1, &As[0][2048 + wofs]);
  gload16(Bp0, &Bs[0][wofs]);
  gload16(Bp1, &Bs[0][2048 + wofs]);

  for (int kt = 0; kt < nkt; ++kt) {
    const int cur = kt & 1;
    __syncthreads();   // vmcnt(0): tile kt resident; buf[cur^1] safe to refill
    if (kt + 1 < nkt) {
      const int k0 = (kt + 1) << 5;
      const int nxt = cur ^ 1;
      gload16(Ap0 + k0, &As[nxt][wofs]);
      gload16(Ap1 + k0, &As[nxt][2048 + wofs]);
      gload16(Bp0 + k0, &Bs[nxt][wofs]);
      gload16(Bp1 + k0, &Bs[nxt][2048 + wofs]);
    }
    bf16x8 af[4], bfv[4];
#pragma unroll
    for (int i = 0; i < 4; ++i)
      af[i] = *reinterpret_cast<const bf16x8*>(&As[cur][a_off0 + i * 512]);
#pragma unroll
    for (int j = 0; j < 4; ++j)
      bfv[j] = *reinterpret_cast<const bf16x8*>(&Bs[cur][b_off0 + j * 512]);
#pragma unroll
    for (int i = 0; i < 4; ++i)
#pragma unroll
      for (int j = 0; j < 4; ++j)
        acc[i][j] = __builtin_amdgcn_mfma_f32_16x16x32_bf16(af[i], bfv[j],
                                                            acc[i][j], 0, 0, 0);
  }

  const int er0 = wr * 64 + ((lane >> 4) << 2);
  const int ec0 = wc * 64 + (lane & 15);
#pragma unroll
  for (int i = 0; i < 4; ++i) {
#pragma unroll
    for (int j = 0; j < 4; ++j) {
#pragma unroll
      for (int r = 0; r < 4; ++r) {
        int row = m0 + er0 + i * 16 + r;
        int col = n0 + ec0 + j * 16;
        if (row >= g.M || col >= g.N) continue;
        float val = acc[i][j][r] * g.scale;
        if constexpr (MODE == 0) {
          g.Cb[z * g.c_bs + (long long)row * g.c_rs + col] = f2b(val);
        } else if constexpr (MODE == 1) {
          long long idx = z * g.c_bs + (long long)row * g.c_rs + col;
          g.Cb[idx] = f2b(b2f(g.Cb[idx]) + val);
        } else if constexpr (MODE == 2) {
          val += g.bias[col];
          int which = col >> 10;
          int h = (col >> 6) & 15;
          int d = col & 63;
          int bb = row >> 9, s = row & 511;
          ushort_t* dst = (which == 0) ? g.qb : (which == 1) ? g.kb : g.vb;
          dst[((long long)(bb * 16 + h) * 512 + s) * 64 + d] = f2b(val);
        } else if constexpr (MODE == 3) {
          long long idx = z * g.c_bs + (long long)row * g.c_rs + col;
          g.Cf[idx] = g.resid[idx] + val + g.bias[col];
        } else if constexpr (MODE == 4) {
          float xv = val + g.bias[col];
          float tv = tanhf(0.7978845608028654f * (xv + 0.044715f * xv * xv * xv));
          g.Cb[z * g.c_bs + (long long)row * g.c_rs + col] =
              f2b(0.5f * xv * (1.f + tv));
        }
      }
    }
  }
}

// ------------------------------------------------------------------ host ----
extern "C" void kernel_launch(void* const* d_in, const int* in_sizes, int n_in,
                              void* d_out, int out_size, void* d_ws,
                              size_t ws_size, hipStream_t stream) {
  const float* x    = (const float*)d_in[0];
  const int*   mask = (const int*)d_in[1];
  const float* Wq   = (const float*)d_in[2];
  const float* bq   = (const float*)d_in[3];
  const float* Wk   = (const float*)d_in[4];
  const float* bk   = (const float*)d_in[5];
  const float* Wv   = (const float*)d_in[6];
  const float* bv   = (const float*)d_in[7];
  const float* Wo   = (const float*)d_in[8];
  const float* bo   = (const float*)d_in[9];
  const float* r_k  = (const float*)d_in[10];
  const float* r_v  = (const float*)d_in[11];
  const float* ln1g = (const float*)d_in[12];
  const float* ln1b = (const float*)d_in[13];
  const float* ln2g = (const float*)d_in[14];
  const float* ln2b = (const float*)d_in[15];
  const float* w1   = (const float*)d_in[16];
  const float* b1   = (const float*)d_in[17];
  const float* w2   = (const float*)d_in[18];
  const float* b2   = (const float*)d_in[19];
  float* out = (float*)d_out;

  char* ws = (char*)d_ws;
  size_t off = 0;
  auto alloc = [&](size_t bytes) -> void* {
    void* p = ws + off;
    off += (bytes + 255) & ~(size_t)255;
    return p;
  };
  ushort_t* wqkv = (ushort_t*)alloc(3072ll * 1024 * 2);
  ushort_t* wo_b = (ushort_t*)alloc(1024ll * 1024 * 2);
  ushort_t* w1_b = (ushort_t*)alloc(4096ll * 1024 * 2);
  ushort_t* w2_b = (ushort_t*)alloc(1024ll * 4096 * 2);
  ushort_t* rk_b = (ushort_t*)alloc(512ll * 512 * 64 * 2);
  ushort_t* rvT  = (ushort_t*)alloc(512ll * 64 * 512 * 2);
  ushort_t* xn   = (ushort_t*)alloc(4096ll * 1024 * 2);  // later: attn_tok
  ushort_t* qb   = (ushort_t*)alloc(128ll * 512 * 64 * 2);  // later: h_bf
  ushort_t* kb   = (ushort_t*)alloc(128ll * 512 * 64 * 2);
  ushort_t* vb   = (ushort_t*)alloc(128ll * 512 * 64 * 2);
  ushort_t* vT   = (ushort_t*)alloc(128ll * 64 * 512 * 2);
  ushort_t* scp  = (ushort_t*)alloc(128ll * 512 * 512 * 2);  // later: mid
  ushort_t* attn = (ushort_t*)alloc(128ll * 512 * 64 * 2);
  float*    x1   = (float*)alloc(4096ll * 1024 * 4);
  float*    bqkv = (float*)alloc(3072 * 4);
  ushort_t* attn_tok = xn;
  ushort_t* h_b = qb;
  ushort_t* mid = scp;

  hipMemcpyAsync(bqkv, bq, 1024 * 4, hipMemcpyDeviceToDevice, stream);
  hipMemcpyAsync(bqkv + 1024, bk, 1024 * 4, hipMemcpyDeviceToDevice, stream);
  hipMemcpyAsync(bqkv + 2048, bv, 1024 * 4, hipMemcpyDeviceToDevice, stream);

  auto cvt = [&](const float* src, ushort_t* dst, long long n) {
    k_f32_to_bf16<<<dim3((unsigned)((n / 4 + 255) / 256)), 256, 0, stream>>>(src, dst, n);
  };
  cvt(Wq, wqkv, 1024ll * 1024);
  cvt(Wk, wqkv + 1024ll * 1024, 1024ll * 1024);
  cvt(Wv, wqkv + 2048ll * 1024, 1024ll * 1024);
  cvt(Wo, wo_b, 1024ll * 1024);
  cvt(w1, w1_b, 4096ll * 1024);
  cvt(w2, w2_b, 1024ll * 4096);
  cvt(r_k, rk_b, 512ll * 512 * 64);
  k_transpose_rv<<<dim3(8, 512), 256, 0, stream>>>(r_v, rvT);

  k_layernorm_bf16<<<1024, 256, 0, stream>>>(x, ln1g, ln1b, xn);

  {  // QKV projection, scatter to [B,H,S,DK]
    GArgs a{};
    a.A = xn; a.B = wqkv; a.a_rs = 1024; a.b_rs = 1024;
    a.M = 4096; a.N = 3072; a.K = 1024; a.scale = 1.f;
    a.bias = bqkv; a.qb = qb; a.kb = kb; a.vb = vb; a.swz = 1;
    k_gemm_bt<2><<<dim3(24, 32, 1), 256, 0, stream>>>(a);
  }

  k_transpose_v<<<dim3(8, 128), 256, 0, stream>>>(vb, vT);

  {  // scores = q.k^T (unscaled), per bh
    GArgs s{};
    s.A = qb; s.B = kb; s.a_bs = 32768; s.b_bs = 32768; s.c_bs = 262144;
    s.a_rs = 64; s.b_rs = 64; s.c_rs = 512;
    s.M = 512; s.N = 512; s.K = 64; s.scale = 1.f; s.Cb = scp;
    k_gemm_bt<0><<<dim3(4, 4, 128), 256, 0, stream>>>(s);
  }
  {  // scores += q . r_k[q]^T, per q-position (M=b*h)
    GArgs r{};
    r.A = qb; r.B = rk_b; r.a_bs = 64; r.b_bs = 32768; r.c_bs = 512;
    r.a_rs = 32768; r.b_rs = 64; r.c_rs = 262144;
    r.M = 128; r.N = 512; r.K = 64; r.scale = 1.f; r.Cb = scp;
    k_gemm_bt<1><<<dim3(4, 1, 512), 256, 0, stream>>>(r);
  }

  k_softmax<<<16384, 256, 0, stream>>>(scp, mask, 0.125f);

  {  // attn = p @ v, per bh
    GArgs pv{};
    pv.A = scp; pv.B = vT; pv.a_bs = 262144; pv.b_bs = 32768; pv.c_bs = 32768;
    pv.a_rs = 512; pv.b_rs = 512; pv.c_rs = 64;
    pv.M = 512; pv.N = 64; pv.K = 512; pv.scale = 1.f; pv.Cb = attn;
    k_gemm_bt<0><<<dim3(1, 4, 128), 256, 0, stream>>>(pv);
  }
  {  // attn += p . r_v[q], per q-position
    GArgs pr{};
    pr.A = scp; pr.B = rvT; pr.a_bs = 512; pr.b_bs = 32768; pr.c_bs = 64;
    pr.a_rs = 262144; pr.b_rs = 512; pr.c_rs = 32768;
    pr.M = 128; pr.N = 64; pr.K = 512; pr.scale = 1.f; pr.Cb = attn;
    k_gemm_bt<1><<<dim3(1, 1, 512), 256, 0, stream>>>(pr);
  }

  k_reshape_attn<<<2048, 256, 0, stream>>>(attn, attn_tok);

  {  // x1 = x + attn_tok @ Wo^T + bo   (fp32)
    GArgs o{};
    o.A = attn_tok; o.B = wo_b; o.a_rs = 1024; o.b_rs = 1024; o.c_rs = 1024;
    o.M = 4096; o.N = 1024; o.K = 1024; o.scale = 1.f;
    o.Cf = x1; o.bias = bo; o.resid = x; o.swz = 1;
    k_gemm_bt<3><<<dim3(8, 32, 1), 256, 0, stream>>>(o);
  }

  k_layernorm_bf16<<<1024, 256, 0, stream>>>(x1, ln2g, ln2b, h_b);

  {  // mid = gelu(h @ w1^T + b1)
    GArgs f1{};
    f1.A = h_b; f1.B = w1_b; f1.a_rs = 1024; f1.b_rs = 1024; f1.c_rs = 4096;
    f1.M = 4096; f1.N = 4096; f1.K = 1024; f1.scale = 1.f;
    f1.Cb = mid; f1.bias = b1; f1.swz = 1;
    k_gemm_bt<4><<<dim3(32, 32, 1), 256, 0, stream>>>(f1);
  }
  {  // out = x1 + mid @ w2^T + b2   (fp32)
    GArgs f2{};
    f2.A = mid; f2.B = w2_b; f2.a_rs = 4096; f2.b_rs = 4096; f2.c_rs = 1024;
    f2.M = 4096; f2.N = 1024; f2.K = 4096; f2.scale = 1.f;
    f2.Cf = out; f2.bias = b2; f2.resid = x1; f2.swz = 1;
    k_gemm_bt<3><<<dim3(8, 32, 1), 256, 0, stream>>>(f2);
  }
}